// Round 13
// baseline (173.861 us; speedup 1.0000x reference)
//
#include <hip/hip_runtime.h>

// CrossAttention fused kernel for MI355X (gfx950) — R27
// R27 = R26 (167.1us) + fp8-e4m3 P3 (Wo weights + AO activations):
//  - R26 confirmed the bytes-lever: fp8 P1 = -15.5us on fused (L2-side bytes,
//    ~50us/GB per R21). Extending to P3 halves the Wo stream (512->256MB) and
//    AO LDS bytes at fixed geometry.
//  - AO race solved: head wv's fp8 AO lands in bytes [cb*2, cb*2+64) of its
//    own rows (low half of its owned 128B range, read-complete at write time);
//    stale q at [cb*2+64, cb*2+128) is never read again. P3 A-frag read:
//    slice ks -> byte ks*16 + (ks>>2)*64 + hi5*8 (dim d at byte d+(d/64)*64).
//  - Wo x128 into e4m3; AO x32; combined descale 1/4096 in epilogue.
//  - P1, P2, kv_proj byte-identical to R26.

#define DQ 512
#define DC 768
#define MCTX 77
#define MPAD 96
#define DH 64

typedef __attribute__((ext_vector_type(8))) short bf16x8;
typedef __attribute__((ext_vector_type(4))) short s16x4;
typedef __attribute__((ext_vector_type(4))) float f32x4;
typedef __attribute__((ext_vector_type(16))) float f32x16;

__device__ __forceinline__ short f2bf(float f) {
    unsigned u = __builtin_bit_cast(unsigned, f);
    u = (u + 0x7FFFu + ((u >> 16) & 1u)) >> 16;
    return (short)u;
}
// packed f32 pair -> bf16 pair (lo in bits[15:0]); RTNE, single VALU op
__device__ __forceinline__ unsigned cvtpk(float lo, float hi) {
    unsigned r;
    asm("v_cvt_pk_bf16_f32 %0, %1, %2" : "=v"(r) : "v"(lo), "v"(hi));
    return r;
}
// 4x f32 -> 4x fp8-e4m3 packed into one dword (byte0=a .. byte3=d)
__device__ __forceinline__ unsigned pk8x4(float a, float b, float c, float d) {
    unsigned r;
    asm("v_cvt_pk_fp8_f32 %0, %1, %2\n\t"
        "v_cvt_pk_fp8_f32 %0, %3, %4 op_sel:[0,0,1]"
        : "=&v"(r)
        : "v"(a), "v"(b), "v"(c), "v"(d));
    return r;
}

#define SWZ(row, byte) ((byte) ^ (((row) & 7) << 4))
#define MFMA(a, b, c) __builtin_amdgcn_mfma_f32_16x16x32_bf16((a), (b), (c), 0, 0, 0)
#define MFMA8(a, b, c) __builtin_amdgcn_mfma_f32_32x32x16_fp8_fp8((a), (b), (c), 0, 0, 0)

#define WQ_SCALE 128.0f
#define WO_SCALE 128.0f
#define AO_SCALE 32.0f

// ---------------------------------------------------------------------------
// Fused weight prep (one launch):
//   blocks 0..127   : pack Wq -> WqF8  (32x32x16-frag flat, fp8 e4m3, x128)
//   blocks 128..255 : pack Wo -> WoF8  (fp8 e4m3, x128)
//   blocks 256..639 : transpose+cast Wk -> WkT [512][768]
//   blocks 640..1023: transpose+cast Wv -> WvT
// ---------------------------------------------------------------------------
__global__ void prep_weights(const float* __restrict__ Wq, const float* __restrict__ Wk,
                             const float* __restrict__ Wv, const float* __restrict__ Wo,
                             unsigned char* __restrict__ WqF8, short* __restrict__ WkT,
                             short* __restrict__ WvT, unsigned char* __restrict__ WoF8) {
    __shared__ float t[32][33];
    int bid = blockIdx.x;
    if (bid < 256) {
        // ---- fp8 pack: K=512, N=512, 32 K-slices of 16 ----
        const float* src = (bid < 128) ? Wq : Wo;
        unsigned char* dst = (bid < 128) ? WqF8 : WoF8;
        int vb = bid & 127;
        int idx = vb * 256 + threadIdx.x;
        int lane = idx & 63;
        int chunk = idx >> 6;
        int tt = chunk % 16, ks = chunk / 16;  // NT = 16, ks in [0,32)
        int n = tt * 32 + (lane & 31);
        int k0 = ks * 16 + (lane >> 5) * 8;
        float v[8];
#pragma unroll
        for (int j = 0; j < 8; ++j) v[j] = src[(size_t)(k0 + j) * 512 + n] * WQ_SCALE;
        uint2 p = make_uint2(pk8x4(v[0], v[1], v[2], v[3]), pk8x4(v[4], v[5], v[6], v[7]));
        *(uint2*)(dst + (size_t)idx * 8) = p;
    } else {
        // ---- transpose_cast: K=768, N=512 ----
        const float* src = (bid < 640) ? Wk : Wv;
        short* dst = (bid < 640) ? WkT : WvT;
        int vb = (bid - 256) % 384;
        int tn = vb % 16, tk = vb / 16;  // ntn = 512>>5 = 16
        int tx = threadIdx.x & 31, ty = threadIdx.x >> 5;
#pragma unroll
        for (int i = 0; i < 32; i += 8)
            t[ty + i][tx] = src[(size_t)(tk * 32 + ty + i) * 512 + tn * 32 + tx];
        __syncthreads();
#pragma unroll
        for (int i = 0; i < 32; i += 8)
            dst[(size_t)(tn * 32 + ty + i) * 768 + tk * 32 + tx] = f2bf(t[tx][ty + i]);
    }
}

// ---------------------------------------------------------------------------
// K: Kb [16][96][512] ([b][ctx][dim], rows 77..95 zero)
// V: VbT [16][512][96] ([b][dim][ctx], ctx 77..95 zero)
// ---------------------------------------------------------------------------
__global__ __launch_bounds__(256, 1) void kv_proj(const float* __restrict__ ctxin,
                                                  const short* __restrict__ WkT,
                                                  const short* __restrict__ WvT,
                                                  short* __restrict__ Kb,
                                                  short* __restrict__ VbT) {
    int b = blockIdx.x >> 2;
    int kv = (blockIdx.x >> 1) & 1;
    int half = blockIdx.x & 1;
    const short* WT = kv ? WvT : WkT;

    __shared__ short A[48 * 768];
    const int tid = threadIdx.x;
    const int lane = tid & 63, wv = tid >> 6;
    const int l15 = lane & 15, l4 = lane >> 4;

#pragma unroll
    for (int it = 0; it < 36; ++it) {
        int id = it * 256 + tid;
        int row = id / 192, col = (id % 192) * 4;
        int gctx = half * 48 + row;
        float4 v = make_float4(0.f, 0.f, 0.f, 0.f);
        if (gctx < MCTX)
            v = ((const float4*)(ctxin + ((size_t)(b * MCTX + gctx)) * DC))[id % 192];
        s16x4 s4;
        s4[0] = f2bf(v.x); s4[1] = f2bf(v.y); s4[2] = f2bf(v.z); s4[3] = f2bf(v.w);
        *(s16x4*)((char*)A + row * 1536 + SWZ(row, col * 2)) = s4;
    }
    __syncthreads();

    f32x4 zf = {0.f, 0.f, 0.f, 0.f};
    f32x4 acc[3][8];
#pragma unroll
    for (int m = 0; m < 3; ++m)
#pragma unroll
        for (int nb = 0; nb < 8; ++nb) acc[m][nb] = zf;

    for (int ks = 0; ks < 24; ++ks) {
        bf16x8 bb[8], aa[3];
#pragma unroll
        for (int nb = 0; nb < 8; ++nb) {
            int n = wv * 128 + nb * 16 + l15;
            bb[nb] = *(const bf16x8*)((const char*)WT + (size_t)n * 1536 + ks * 64 + l4 * 16);
        }
#pragma unroll
        for (int m = 0; m < 3; ++m) {
            int row = m * 16 + l15;
            aa[m] = *(const bf16x8*)((char*)A + row * 1536 + SWZ(row, ks * 64 + l4 * 16));
        }
#pragma unroll
        for (int nb = 0; nb < 8; ++nb)
#pragma unroll
            for (int m = 0; m < 3; ++m) acc[m][nb] = MFMA(aa[m], bb[nb], acc[m][nb]);
    }

    if (kv == 0) {
#pragma unroll
        for (int m = 0; m < 3; ++m)
#pragma unroll
            for (int nb = 0; nb < 8; ++nb)
#pragma unroll
                for (int r = 0; r < 4; ++r) {
                    int ctxi = half * 48 + m * 16 + l4 * 4 + r;
                    int col = wv * 128 + nb * 16 + l15;
                    Kb[((size_t)(b * MPAD + ctxi)) * 512 + col] = f2bf(acc[m][nb][r]);
                }
    } else {
#pragma unroll
        for (int m = 0; m < 3; ++m)
#pragma unroll
            for (int nb = 0; nb < 8; ++nb)
#pragma unroll
                for (int r = 0; r < 4; ++r) {
                    int ctxi = half * 48 + m * 16 + l4 * 4 + r;
                    int col = wv * 128 + nb * 16 + l15;
                    VbT[((size_t)(b * 512 + col)) * MPAD + ctxi] = f2bf(acc[m][nb][r]);
                }
    }
}

// ---------------------------------------------------------------------------
// Fused: LN(fp8 h) -> Qproj (fp8 32x32, swapped) -> attention (bf16 16x16)
//        -> Oproj (fp8 32x32, direct) + epilogue
// grid: 1024 blocks (XCD-swizzled), 512 threads (8 waves), 64 rows/block
// ---------------------------------------------------------------------------
__global__ __launch_bounds__(512, 4) void fused_attn(
    const float* __restrict__ x, const float* __restrict__ gamma,
    const float* __restrict__ beta, const unsigned char* __restrict__ WqF8,
    const unsigned char* __restrict__ WoF8, const short* __restrict__ Kb,
    const short* __restrict__ VbT, const float* __restrict__ bo,
    float* __restrict__ out) {
    __shared__ short A[64 * 512];  // 64KB: h(fp8) -> q(bf16) -> AO(fp8), XOR swz

    const int tid = threadIdx.x;
    const int lane = tid & 63, wv = tid >> 6;  // wv = head
    const int l15 = lane & 15, l4 = lane >> 4;
    const int l31 = lane & 31, hi5 = lane >> 5;
    const int swz = (blockIdx.x & 7) * 128 + (blockIdx.x >> 3);  // XCD-chunked
    const int b = swz >> 6;
    const size_t rowbase = (size_t)swz * 64;
    const int cb = wv * 64;  // this wave's 64 cols == head wv's dims

    // ---- Phase 0: LayerNorm -> h fp8 in A bytes [0,512)/row ----
    {
        float g[8], be[8];
        float4 g0 = ((const float4*)gamma)[lane * 2], g1 = ((const float4*)gamma)[lane * 2 + 1];
        float4 b0 = ((const float4*)beta)[lane * 2], b1 = ((const float4*)beta)[lane * 2 + 1];
        g[0] = g0.x; g[1] = g0.y; g[2] = g0.z; g[3] = g0.w;
        g[4] = g1.x; g[5] = g1.y; g[6] = g1.z; g[7] = g1.w;
        be[0] = b0.x; be[1] = b0.y; be[2] = b0.z; be[3] = b0.w;
        be[4] = b1.x; be[5] = b1.y; be[6] = b1.z; be[7] = b1.w;
#pragma unroll 1
        for (int g4 = 0; g4 < 2; ++g4) {
            float4 v0[4], v1[4];
#pragma unroll
            for (int j = 0; j < 4; ++j) {
                int row = wv * 8 + g4 * 4 + j;
                const float4* xp = (const float4*)(x + (rowbase + row) * DQ);
                v0[j] = xp[lane * 2];
                v1[j] = xp[lane * 2 + 1];
            }
#pragma unroll
            for (int j = 0; j < 4; ++j) {
                int row = wv * 8 + g4 * 4 + j;
                float vv[8] = {v0[j].x, v0[j].y, v0[j].z, v0[j].w,
                               v1[j].x, v1[j].y, v1[j].z, v1[j].w};
                float s = 0.f, s2 = 0.f;
#pragma unroll
                for (int i = 0; i < 8; ++i) { s += vv[i]; s2 = fmaf(vv[i], vv[i], s2); }
#pragma unroll
                for (int m = 1; m < 64; m <<= 1) {
                    s += __shfl_xor(s, m);
                    s2 += __shfl_xor(s2, m);
                }
                float mu = s * (1.f / 512.f);
                float var = s2 * (1.f / 512.f) - mu * mu;
                float rs = rsqrtf(var + 1e-5f);
                float hn[8];
#pragma unroll
                for (int i = 0; i < 8; ++i) hn[i] = (vv[i] - mu) * rs * g[i] + be[i];
                uint2 hv = make_uint2(pk8x4(hn[0], hn[1], hn[2], hn[3]),
                                      pk8x4(hn[4], hn[5], hn[6], hn[7]));
                *(uint2*)((char*)A + row * 1024 + SWZ(row, lane * 8)) = hv;
            }
        }
    }

    f32x4 zf = {0.f, 0.f, 0.f, 0.f};

// fp8 flat weight frag load (8B): tile wv*2+tt, K-slice ks (K=16/slice)
#define LDWF8(dst, BASE, ks)                                                               \
    _Pragma("unroll") for (int tt = 0; tt < 2; ++tt) {                                     \
        (dst)[tt] = *(const long*)((BASE) +                                                \
            (size_t)((((ks)*16 + wv * 2 + tt) * 64 + lane)) * 8);                          \
    }
// fp8 h frag read (8B): rows tt*32+l31, bytes ks*16 + hi5*8
#define LDT8(dst, ks)                                                                      \
    _Pragma("unroll") for (int tt = 0; tt < 2; ++tt) {                                     \
        int row = tt * 32 + l31;                                                           \
        (dst)[tt] = *(const long*)((char*)A + row * 1024 +                                 \
                                   SWZ(row, (ks)*16 + hi5 * 8));                           \
    }
// fp8 AO frag read (8B): dim d at byte d+(d/64)*64 -> slice ks at
// ks*16 + (ks>>2)*64 + hi5*8
#define LDT8AO(dst, ks)                                                                    \
    _Pragma("unroll") for (int tt = 0; tt < 2; ++tt) {                                     \
        int row = tt * 32 + l31;                                                           \
        (dst)[tt] = *(const long*)((char*)A + row * 1024 +                                 \
                                   SWZ(row, (ks)*16 + ((ks) >> 2) * 64 + hi5 * 8));        \
    }
// K-slice step, SWAPPED fp8 (phase 1): ACC[mt][nt] += W[mt] * h[nt]
#define GSTEP_Q8(W, ACC, kk)                                                               \
    {                                                                                      \
        long hb[2];                                                                        \
        LDT8(hb, (kk));                                                                    \
        _Pragma("unroll") for (int mt = 0; mt < 2; ++mt)                                   \
            _Pragma("unroll") for (int nt = 0; nt < 2; ++nt)                               \
                ACC[mt][nt] = MFMA8((W)[mt], hb[nt], ACC[mt][nt]);                         \
        LDWF8((W), WqF8, (kk) + 4);                                                        \
    }
#define GSTEP_Q8_NR(W, ACC, kk)                                                            \
    {                                                                                      \
        long hb[2];                                                                        \
        LDT8(hb, (kk));                                                                    \
        _Pragma("unroll") for (int mt = 0; mt < 2; ++mt)                                   \
            _Pragma("unroll") for (int nt = 0; nt < 2; ++nt)                               \
                ACC[mt][nt] = MFMA8((W)[mt], hb[nt], ACC[mt][nt]);                         \
    }
// K-slice step, DIRECT fp8 (phase 3): ACC[mt][ct] += AO[mt] * W[ct]
#define GSTEP_O8(W, ACC, kk)                                                               \
    {                                                                                      \
        long ab[2];                                                                        \
        LDT8AO(ab, (kk));                                                                  \
        _Pragma("unroll") for (int mt = 0; mt < 2; ++mt)                                   \
            _Pragma("unroll") for (int ct = 0; ct < 2; ++ct)                               \
                ACC[mt][ct] = MFMA8(ab[mt], (W)[ct], ACC[mt][ct]);                         \
        LDWF8((W), WoF8, (kk) + 4);                                                        \
    }
#define GSTEP_O8_NR(W, ACC, kk)                                                            \
    {                                                                                      \
        long ab[2];                                                                        \
        LDT8AO(ab, (kk));                                                                  \
        _Pragma("unroll") for (int mt = 0; mt < 2; ++mt)                                   \
            _Pragma("unroll") for (int ct = 0; ct < 2; ++ct)                               \
                ACC[mt][ct] = MFMA8(ab[mt], (W)[ct], ACC[mt][ct]);                         \
    }

    // ---- Phase 1: Q = h @ Wq via swapped fp8 32x32: D = mfma(WqF8, h^T) = q^T ----
    {
        long w0[2], w1[2], w2[2], w3[2];
        LDWF8(w0, WqF8, 0);  // 4-deep prefetch issued before the barrier
        LDWF8(w1, WqF8, 1);
        LDWF8(w2, WqF8, 2);
        LDWF8(w3, WqF8, 3);
        __syncthreads();   // h complete

        f32x16 qa[2][2];  // [mt=qcol tile][nt=qrow tile]
#pragma unroll
        for (int mt = 0; mt < 2; ++mt)
#pragma unroll
            for (int nt = 0; nt < 2; ++nt)
#pragma unroll
                for (int i = 0; i < 16; ++i) qa[mt][nt][i] = 0.f;

#pragma unroll 1
        for (int ks = 0; ks < 28; ks += 4) {  // refills target slices 4..31
            GSTEP_Q8(w0, qa, ks)
            GSTEP_Q8(w1, qa, ks + 1)
            GSTEP_Q8(w2, qa, ks + 2)
            GSTEP_Q8(w3, qa, ks + 3)
        }
        GSTEP_Q8_NR(w0, qa, 28)  // last 4 slices: no refill, no over-read
        GSTEP_Q8_NR(w1, qa, 29)
        GSTEP_Q8_NR(w2, qa, 30)
        GSTEP_Q8_NR(w3, qa, 31)
        __syncthreads();  // all waves done reading h

        // q writeback: fold 0.125 QK scale AND 1/WQ_SCALE fp8 descale
        const float QS = 0.125f / WQ_SCALE;
#pragma unroll
        for (int mt = 0; mt < 2; ++mt)
#pragma unroll
            for (int nt = 0; nt < 2; ++nt)
#pragma unroll
                for (int g = 0; g < 4; ++g) {
                    uint2 qv = make_uint2(
                        cvtpk(qa[mt][nt][g * 4] * QS, qa[mt][nt][g * 4 + 1] * QS),
                        cvtpk(qa[mt][nt][g * 4 + 2] * QS, qa[mt][nt][g * 4 + 3] * QS));
                    int row = nt * 32 + l31;
                    int colb = (cb + mt * 32 + 8 * g + 4 * hi5) * 2;
                    *(uint2*)((char*)A + row * 1024 + SWZ(row, colb)) = qv;
                }
        // no barrier: each wave reads only its own 64 columns from here
    }

    // ---- Phase 2: attention for head wv (16x16 bf16, swapped PV, P in regs) ----
    {
        const int srcA = ((l4 & 1) << 5) + l15;
        const int srcB = srcA + 16;
        const bool hi = (l4 >> 1) != 0;

        // V fragments are rp-invariant: hoist out of the rp loop (48 VGPRs)
        bf16x8 vR[3][4];
#pragma unroll
        for (int ks = 0; ks < 3; ++ks)
#pragma unroll
            for (int nb = 0; nb < 4; ++nb)
                vR[ks][nb] = *(const bf16x8*)(VbT +
                                              ((size_t)(b * 512 + cb + nb * 16 + l15)) * MPAD +
                                              ks * 32 + l4 * 8);

#pragma unroll 1
        for (int rp = 0; rp < 4; ++rp) {
            bf16x8 qf0, qf1;
            {
                int qrow = rp * 16 + l15;
                qf0 = *(const bf16x8*)((char*)A + qrow * 1024 + SWZ(qrow, cb * 2 + l4 * 16));
                qf1 = *(const bf16x8*)((char*)A + qrow * 1024 + SWZ(qrow, cb * 2 + 64 + l4 * 16));
            }
            f32x4 sc[5];
            __builtin_amdgcn_s_setprio(1);
#pragma unroll
            for (int f = 0; f < 5; ++f) {
                bf16x8 k0 = *(const bf16x8*)(Kb + ((size_t)(b * MPAD + f * 16 + l15)) * 512 +
                                             cb + l4 * 8);
                bf16x8 k1 = *(const bf16x8*)(Kb + ((size_t)(b * MPAD + f * 16 + l15)) * 512 +
                                             cb + 32 + l4 * 8);
                sc[f] = MFMA(k0, qf0, zf);
                sc[f] = MFMA(k1, qf1, sc[f]);
            }
            __builtin_amdgcn_s_setprio(0);
            // q was pre-scaled at writeback; scores are final here
            float m = -1e30f;
#pragma unroll
            for (int f = 0; f < 5; ++f)
#pragma unroll
                for (int r = 0; r < 4; ++r) {
                    float v = sc[f][r];
                    if (f == 4 && (64 + l4 * 4 + r) >= MCTX) v = -1e30f;
                    sc[f][r] = v;
                    m = fmaxf(m, v);
                }
            m = fmaxf(m, __shfl_xor(m, 16));
            m = fmaxf(m, __shfl_xor(m, 32));
            float s = 0.f;
#pragma unroll
            for (int f = 0; f < 5; ++f)
#pragma unroll
                for (int r = 0; r < 4; ++r) {
                    float p = __expf(sc[f][r] - m);
                    sc[f][r] = p;
                    s += p;
                }
            s += __shfl_xor(s, 16);
            s += __shfl_xor(s, 32);
            float inv = 1.f / s;
            unsigned pk[6][2];
#pragma unroll
            for (int f = 0; f < 5; ++f) {
                pk[f][0] = cvtpk(sc[f][0] * inv, sc[f][1] * inv);
                pk[f][1] = cvtpk(sc[f][2] * inv, sc[f][3] * inv);
            }
            pk[5][0] = 0; pk[5][1] = 0;
            unsigned pa[3][4];
#pragma unroll
            for (int ks = 0; ks < 3; ++ks) {
                unsigned aL0 = __shfl((int)pk[2 * ks][0], srcA);
                unsigned aL1 = __shfl((int)pk[2 * ks][1], srcA);
                unsigned aH0 = __shfl((int)pk[2 * ks + 1][0], srcA);
                unsigned aH1 = __shfl((int)pk[2 * ks + 1][1], srcA);
                unsigned bL0 = __shfl((int)pk[2 * ks][0], srcB);
                unsigned bL1 = __shfl((int)pk[2 * ks][1], srcB);
                unsigned bH0 = __shfl((int)pk[2 * ks + 1][0], srcB);
                unsigned bH1 = __shfl((int)pk[2 * ks + 1][1], srcB);
                pa[ks][0] = hi ? aH0 : aL0;
                pa[ks][1] = hi ? aH1 : aL1;
                pa[ks][2] = hi ? bH0 : bL0;
                pa[ks][3] = hi ? bH1 : bL1;
            }
            // PV swapped: D = mfma(A=V^T frag, B=P frag) = (PV)^T
            f32x4 ov[4];
#pragma unroll
            for (int nb = 0; nb < 4; ++nb) ov[nb] = zf;
            __builtin_amdgcn_s_setprio(1);
#pragma unroll
            for (int ks = 0; ks < 3; ++ks) {
                bf16x8 ap = __builtin_bit_cast(bf16x8, pa[ks]);
#pragma unroll
                for (int nb = 0; nb < 4; ++nb) {
                    ov[nb] = MFMA(vR[ks][nb], ap, ov[nb]);  // swapped args, V in regs
                }
            }
            __builtin_amdgcn_s_setprio(0);
            // AO writeback fp8 x32: dword at byte cb*2 + nb*16 + l4*4 of own rows
#pragma unroll
            for (int nb = 0; nb < 4; ++nb) {
                unsigned av = pk8x4(ov[nb][0] * AO_SCALE, ov[nb][1] * AO_SCALE,
                                    ov[nb][2] * AO_SCALE, ov[nb][3] * AO_SCALE);
                int row = rp * 16 + l15;
                int colb = cb * 2 + nb * 16 + l4 * 4;
                *(unsigned*)((char*)A + row * 1024 + SWZ(row, colb)) = av;
            }
        }
    }

    // ---- Phase 3: O-proj fp8 32x32 (K=512, direct) + residual + bias ----
    {
        long w0[2], w1[2], w2[2], w3[2];
        LDWF8(w0, WoF8, 0);  // 4-deep prefetch issued before the barrier
        LDWF8(w1, WoF8, 1);
        LDWF8(w2, WoF8, 2);
        LDWF8(w3, WoF8, 3);
        __syncthreads();   // AO complete across all waves

        f32x16 oa[2][2];  // [mt=row tile][ct=col tile]
#pragma unroll
        for (int mt = 0; mt < 2; ++mt)
#pragma unroll
            for (int ct = 0; ct < 2; ++ct)
#pragma unroll
                for (int i = 0; i < 16; ++i) oa[mt][ct][i] = 0.f;

#pragma unroll 1
        for (int ks = 0; ks < 28; ks += 4) {  // refills target slices 4..31
            GSTEP_O8(w0, oa, ks)
            GSTEP_O8(w1, oa, ks + 1)
            GSTEP_O8(w2, oa, ks + 2)
            GSTEP_O8(w3, oa, ks + 3)
        }
        GSTEP_O8_NR(w0, oa, 28)  // last 4 slices: no refill, no over-read
        GSTEP_O8_NR(w1, oa, 29)
        GSTEP_O8_NR(w2, oa, 30)
        GSTEP_O8_NR(w3, oa, 31)

        // epilogue: out = x + oa/(WO_SCALE*AO_SCALE) + bo
        const float OS = 1.0f / (WO_SCALE * AO_SCALE);
#pragma unroll
        for (int mt = 0; mt < 2; ++mt)
#pragma unroll
            for (int ct = 0; ct < 2; ++ct) {
                int col = cb + ct * 32 + l31;
                float bov = bo[col];
                float xv[16];
#pragma unroll
                for (int rg = 0; rg < 16; ++rg) {
                    int row = mt * 32 + (rg & 3) + 8 * (rg >> 2) + 4 * hi5;
                    xv[rg] = x[(rowbase + row) * DQ + col];
                }
#pragma unroll
                for (int rg = 0; rg < 16; ++rg) {
                    int row = mt * 32 + (rg & 3) + 8 * (rg >> 2) + 4 * hi5;
                    size_t gi = (rowbase + row) * DQ + col;
                    out[gi] = xv[rg] + oa[mt][ct][rg] * OS + bov;
                }
            }
    }
}

// ---------------------------------------------------------------------------
extern "C" void kernel_launch(void* const* d_in, const int* in_sizes, int n_in,
                              void* d_out, int out_size, void* d_ws, size_t ws_size,
                              hipStream_t stream) {
    const float* x = (const float*)d_in[0];
    const float* ctx = (const float*)d_in[1];
    const float* gamma = (const float*)d_in[2];
    const float* beta = (const float*)d_in[3];
    const float* Wq = (const float*)d_in[4];
    const float* Wk = (const float*)d_in[5];
    const float* Wv = (const float*)d_in[6];
    const float* Wo = (const float*)d_in[7];
    const float* bo = (const float*)d_in[8];
    float* out = (float*)d_out;

    char* ws = (char*)d_ws;
    unsigned char* WqF8 = (unsigned char*)(ws + 0);       // fp8 flat [32ks][16t][64lane][8B]
    unsigned char* WoF8 = (unsigned char*)(ws + 262144);  // fp8 flat
    short* WkT = (short*)(ws + 524288);   // [512][768] row-major W^T
    short* WvT = (short*)(ws + 1310720);  // [512][768]
    short* Kb = (short*)(ws + 2621440);   // [16][96][512]  K: [b][ctx][dim]
    short* VbT = (short*)(ws + 4194304);  // [16][512][96]  V: [b][dim][ctx]

    prep_weights<<<1024, 256, 0, stream>>>(Wq, Wk, Wv, Wo, WqF8, WkT, WvT, WoF8);
    kv_proj<<<64, 256, 0, stream>>>(ctx, WkT, WvT, Kb, VbT);
    fused_attn<<<1024, 512, 0, stream>>>(x, gamma, beta, WqF8, WoF8, Kb, VbT, bo, out);
}

// Round 14
// 166.454 us; speedup vs baseline: 1.0445x; 1.0445x over previous
//
#include <hip/hip_runtime.h>

// CrossAttention fused kernel for MI355X (gfx950) — R28 (FINAL = R26 restored)
// R27 post-mortem: fp8 P3 (Wo+AO) REGRESSED (fused 159.9->164.9, FETCH +18MB):
// dependent pk8x4 chain on P2's per-rp tail + fragmented AO byte-mapping cost
// more than the halved Wo stream saved. fp8 pays on streaming paths (P1:
// -15.5us), loses on serial paths (P3). Reverted to R26 exactly.
// Session: 194.6 -> 167.1us. Best config: R23 structure (R18 fused_attn +
// fused prep, 3 launches) + fp8-e4m3 P1 (Wq weights x128 + h activations).

#define DQ 512
#define DC 768
#define MCTX 77
#define MPAD 96
#define DH 64

typedef __attribute__((ext_vector_type(8))) short bf16x8;
typedef __attribute__((ext_vector_type(4))) short s16x4;
typedef __attribute__((ext_vector_type(4))) float f32x4;
typedef __attribute__((ext_vector_type(16))) float f32x16;

__device__ __forceinline__ short f2bf(float f) {
    unsigned u = __builtin_bit_cast(unsigned, f);
    u = (u + 0x7FFFu + ((u >> 16) & 1u)) >> 16;
    return (short)u;
}
// packed f32 pair -> bf16 pair (lo in bits[15:0]); RTNE, single VALU op
__device__ __forceinline__ unsigned cvtpk(float lo, float hi) {
    unsigned r;
    asm("v_cvt_pk_bf16_f32 %0, %1, %2" : "=v"(r) : "v"(lo), "v"(hi));
    return r;
}
// 4x f32 -> 4x fp8-e4m3 packed into one dword (byte0=a .. byte3=d)
__device__ __forceinline__ unsigned pk8x4(float a, float b, float c, float d) {
    unsigned r;
    asm("v_cvt_pk_fp8_f32 %0, %1, %2\n\t"
        "v_cvt_pk_fp8_f32 %0, %3, %4 op_sel:[0,0,1]"
        : "=&v"(r)
        : "v"(a), "v"(b), "v"(c), "v"(d));
    return r;
}

#define SWZ(row, byte) ((byte) ^ (((row) & 7) << 4))
#define MFMA(a, b, c) __builtin_amdgcn_mfma_f32_16x16x32_bf16((a), (b), (c), 0, 0, 0)
#define MFMA32(a, b, c) __builtin_amdgcn_mfma_f32_32x32x16_bf16((a), (b), (c), 0, 0, 0)
#define MFMA8(a, b, c) __builtin_amdgcn_mfma_f32_32x32x16_fp8_fp8((a), (b), (c), 0, 0, 0)

#define WQ_SCALE 128.0f

// ---------------------------------------------------------------------------
// Fused weight prep (one launch):
//   blocks 0..127   : pack Wq -> WqF8  (32x32x16-frag flat, fp8 e4m3, x128)
//   blocks 128..255 : pack Wo -> WoF   (bf16 flat)
//   blocks 256..639 : transpose+cast Wk -> WkT [512][768]
//   blocks 640..1023: transpose+cast Wv -> WvT
// ---------------------------------------------------------------------------
__global__ void prep_weights(const float* __restrict__ Wq, const float* __restrict__ Wk,
                             const float* __restrict__ Wv, const float* __restrict__ Wo,
                             unsigned char* __restrict__ WqF8, short* __restrict__ WkT,
                             short* __restrict__ WvT, short* __restrict__ WoF) {
    __shared__ float t[32][33];
    int bid = blockIdx.x;
    if (bid < 128) {
        // ---- fp8 pack Wq: K=512, N=512, 32 K-slices of 16 ----
        int idx = bid * 256 + threadIdx.x;
        int lane = idx & 63;
        int chunk = idx >> 6;
        int tt = chunk % 16, ks = chunk / 16;  // NT = 16, ks in [0,32)
        int n = tt * 32 + (lane & 31);
        int k0 = ks * 16 + (lane >> 5) * 8;
        float v[8];
#pragma unroll
        for (int j = 0; j < 8; ++j) v[j] = Wq[(size_t)(k0 + j) * 512 + n] * WQ_SCALE;
        uint2 p = make_uint2(pk8x4(v[0], v[1], v[2], v[3]), pk8x4(v[4], v[5], v[6], v[7]));
        *(uint2*)(WqF8 + (size_t)idx * 8) = p;
    } else if (bid < 256) {
        // ---- bf16 pack Wo: K=512, N=512 ----
        int vb = bid - 128;
        int idx = vb * 256 + threadIdx.x;
        int lane = idx & 63;
        int chunk = idx >> 6;
        int tt = chunk % 16, ks = chunk / 16;
        int n = tt * 32 + (lane & 31);
        int k0 = ks * 16 + (lane >> 5) * 8;
        bf16x8 v;
#pragma unroll
        for (int j = 0; j < 8; ++j) v[j] = f2bf(Wo[(size_t)(k0 + j) * 512 + n]);
        *(bf16x8*)(WoF + (size_t)idx * 8) = v;
    } else {
        // ---- transpose_cast: K=768, N=512 ----
        const float* src = (bid < 640) ? Wk : Wv;
        short* dst = (bid < 640) ? WkT : WvT;
        int vb = (bid - 256) % 384;
        int tn = vb % 16, tk = vb / 16;  // ntn = 512>>5 = 16
        int tx = threadIdx.x & 31, ty = threadIdx.x >> 5;
#pragma unroll
        for (int i = 0; i < 32; i += 8)
            t[ty + i][tx] = src[(size_t)(tk * 32 + ty + i) * 512 + tn * 32 + tx];
        __syncthreads();
#pragma unroll
        for (int i = 0; i < 32; i += 8)
            dst[(size_t)(tn * 32 + ty + i) * 768 + tk * 32 + tx] = f2bf(t[tx][ty + i]);
    }
}

// ---------------------------------------------------------------------------
// K: Kb [16][96][512] ([b][ctx][dim], rows 77..95 zero)
// V: VbT [16][512][96] ([b][dim][ctx], ctx 77..95 zero)
// ---------------------------------------------------------------------------
__global__ __launch_bounds__(256, 1) void kv_proj(const float* __restrict__ ctxin,
                                                  const short* __restrict__ WkT,
                                                  const short* __restrict__ WvT,
                                                  short* __restrict__ Kb,
                                                  short* __restrict__ VbT) {
    int b = blockIdx.x >> 2;
    int kv = (blockIdx.x >> 1) & 1;
    int half = blockIdx.x & 1;
    const short* WT = kv ? WvT : WkT;

    __shared__ short A[48 * 768];
    const int tid = threadIdx.x;
    const int lane = tid & 63, wv = tid >> 6;
    const int l15 = lane & 15, l4 = lane >> 4;

#pragma unroll
    for (int it = 0; it < 36; ++it) {
        int id = it * 256 + tid;
        int row = id / 192, col = (id % 192) * 4;
        int gctx = half * 48 + row;
        float4 v = make_float4(0.f, 0.f, 0.f, 0.f);
        if (gctx < MCTX)
            v = ((const float4*)(ctxin + ((size_t)(b * MCTX + gctx)) * DC))[id % 192];
        s16x4 s4;
        s4[0] = f2bf(v.x); s4[1] = f2bf(v.y); s4[2] = f2bf(v.z); s4[3] = f2bf(v.w);
        *(s16x4*)((char*)A + row * 1536 + SWZ(row, col * 2)) = s4;
    }
    __syncthreads();

    f32x4 zf = {0.f, 0.f, 0.f, 0.f};
    f32x4 acc[3][8];
#pragma unroll
    for (int m = 0; m < 3; ++m)
#pragma unroll
        for (int nb = 0; nb < 8; ++nb) acc[m][nb] = zf;

    for (int ks = 0; ks < 24; ++ks) {
        bf16x8 bb[8], aa[3];
#pragma unroll
        for (int nb = 0; nb < 8; ++nb) {
            int n = wv * 128 + nb * 16 + l15;
            bb[nb] = *(const bf16x8*)((const char*)WT + (size_t)n * 1536 + ks * 64 + l4 * 16);
        }
#pragma unroll
        for (int m = 0; m < 3; ++m) {
            int row = m * 16 + l15;
            aa[m] = *(const bf16x8*)((char*)A + row * 1536 + SWZ(row, ks * 64 + l4 * 16));
        }
#pragma unroll
        for (int nb = 0; nb < 8; ++nb)
#pragma unroll
            for (int m = 0; m < 3; ++m) acc[m][nb] = MFMA(aa[m], bb[nb], acc[m][nb]);
    }

    if (kv == 0) {
#pragma unroll
        for (int m = 0; m < 3; ++m)
#pragma unroll
            for (int nb = 0; nb < 8; ++nb)
#pragma unroll
                for (int r = 0; r < 4; ++r) {
                    int ctxi = half * 48 + m * 16 + l4 * 4 + r;
                    int col = wv * 128 + nb * 16 + l15;
                    Kb[((size_t)(b * MPAD + ctxi)) * 512 + col] = f2bf(acc[m][nb][r]);
                }
    } else {
#pragma unroll
        for (int m = 0; m < 3; ++m)
#pragma unroll
            for (int nb = 0; nb < 8; ++nb)
#pragma unroll
                for (int r = 0; r < 4; ++r) {
                    int ctxi = half * 48 + m * 16 + l4 * 4 + r;
                    int col = wv * 128 + nb * 16 + l15;
                    VbT[((size_t)(b * 512 + col)) * MPAD + ctxi] = f2bf(acc[m][nb][r]);
                }
    }
}

// ---------------------------------------------------------------------------
// Fused: LN(fp8 h) -> Qproj (32x32 fp8, swapped) -> attention (16x16 bf16)
//        -> Oproj (32x32 bf16, direct) + epilogue
// grid: 1024 blocks (XCD-swizzled), 512 threads (8 waves), 64 rows/block
// ---------------------------------------------------------------------------
__global__ __launch_bounds__(512, 4) void fused_attn(
    const float* __restrict__ x, const float* __restrict__ gamma,
    const float* __restrict__ beta, const unsigned char* __restrict__ WqF8,
    const short* __restrict__ WoF, const short* __restrict__ Kb,
    const short* __restrict__ VbT, const float* __restrict__ bo,
    float* __restrict__ out) {
    __shared__ short A[64 * 512];  // 64KB: h(fp8) -> q(bf16) -> AO, rows 1024B, XOR swz

    const int tid = threadIdx.x;
    const int lane = tid & 63, wv = tid >> 6;  // wv = head
    const int l15 = lane & 15, l4 = lane >> 4;
    const int l31 = lane & 31, hi5 = lane >> 5;
    const int swz = (blockIdx.x & 7) * 128 + (blockIdx.x >> 3);  // XCD-chunked
    const int b = swz >> 6;
    const size_t rowbase = (size_t)swz * 64;
    const int cb = wv * 64;  // this wave's 64 cols == head wv's dims

    // ---- Phase 0: LayerNorm -> h fp8 in A bytes [0,512)/row ----
    {
        float g[8], be[8];
        float4 g0 = ((const float4*)gamma)[lane * 2], g1 = ((const float4*)gamma)[lane * 2 + 1];
        float4 b0 = ((const float4*)beta)[lane * 2], b1 = ((const float4*)beta)[lane * 2 + 1];
        g[0] = g0.x; g[1] = g0.y; g[2] = g0.z; g[3] = g0.w;
        g[4] = g1.x; g[5] = g1.y; g[6] = g1.z; g[7] = g1.w;
        be[0] = b0.x; be[1] = b0.y; be[2] = b0.z; be[3] = b0.w;
        be[4] = b1.x; be[5] = b1.y; be[6] = b1.z; be[7] = b1.w;
#pragma unroll 1
        for (int g4 = 0; g4 < 2; ++g4) {
            float4 v0[4], v1[4];
#pragma unroll
            for (int j = 0; j < 4; ++j) {
                int row = wv * 8 + g4 * 4 + j;
                const float4* xp = (const float4*)(x + (rowbase + row) * DQ);
                v0[j] = xp[lane * 2];
                v1[j] = xp[lane * 2 + 1];
            }
#pragma unroll
            for (int j = 0; j < 4; ++j) {
                int row = wv * 8 + g4 * 4 + j;
                float vv[8] = {v0[j].x, v0[j].y, v0[j].z, v0[j].w,
                               v1[j].x, v1[j].y, v1[j].z, v1[j].w};
                float s = 0.f, s2 = 0.f;
#pragma unroll
                for (int i = 0; i < 8; ++i) { s += vv[i]; s2 = fmaf(vv[i], vv[i], s2); }
#pragma unroll
                for (int m = 1; m < 64; m <<= 1) {
                    s += __shfl_xor(s, m);
                    s2 += __shfl_xor(s2, m);
                }
                float mu = s * (1.f / 512.f);
                float var = s2 * (1.f / 512.f) - mu * mu;
                float rs = rsqrtf(var + 1e-5f);
                float hn[8];
#pragma unroll
                for (int i = 0; i < 8; ++i) hn[i] = (vv[i] - mu) * rs * g[i] + be[i];
                uint2 hv = make_uint2(pk8x4(hn[0], hn[1], hn[2], hn[3]),
                                      pk8x4(hn[4], hn[5], hn[6], hn[7]));
                *(uint2*)((char*)A + row * 1024 + SWZ(row, lane * 8)) = hv;
            }
        }
    }

    f32x4 zf = {0.f, 0.f, 0.f, 0.f};

// fp8 flat weight frag load (8B): tile wv*2+tt, K-slice ks (K=16/slice)
#define LDWF8(dst, ks)                                                                     \
    _Pragma("unroll") for (int tt = 0; tt < 2; ++tt) {                                     \
        (dst)[tt] = *(const long*)(WqF8 +                                                  \
            (size_t)((((ks)*16 + wv * 2 + tt) * 64 + lane)) * 8);                          \
    }
// fp8 h frag read (8B): rows tt*32+l31, bytes ks*16 + hi5*8
#define LDT8(dst, ks)                                                                      \
    _Pragma("unroll") for (int tt = 0; tt < 2; ++tt) {                                     \
        int row = tt * 32 + l31;                                                           \
        (dst)[tt] = *(const long*)((char*)A + row * 1024 +                                 \
                                   SWZ(row, (ks)*16 + hi5 * 8));                           \
    }
// K-slice step, SWAPPED fp8 (phase 1): ACC[mt][nt] += W[mt] * h[nt]
#define GSTEP_Q8(W, ACC, kk)                                                               \
    {                                                                                      \
        long hb[2];                                                                        \
        LDT8(hb, (kk));                                                                    \
        _Pragma("unroll") for (int mt = 0; mt < 2; ++mt)                                   \
            _Pragma("unroll") for (int nt = 0; nt < 2; ++nt)                               \
                ACC[mt][nt] = MFMA8((W)[mt], hb[nt], ACC[mt][nt]);                         \
        LDWF8((W), (kk) + 4);                                                              \
    }
#define GSTEP_Q8_NR(W, ACC, kk)                                                            \
    {                                                                                      \
        long hb[2];                                                                        \
        LDT8(hb, (kk));                                                                    \
        _Pragma("unroll") for (int mt = 0; mt < 2; ++mt)                                   \
            _Pragma("unroll") for (int nt = 0; nt < 2; ++nt)                               \
                ACC[mt][nt] = MFMA8((W)[mt], hb[nt], ACC[mt][nt]);                         \
    }
// bf16 weight frag load (phase 3, unchanged)
#define LDWF(dst, W, ks)                                                                   \
    _Pragma("unroll") for (int tt = 0; tt < 2; ++tt) {                                     \
        (dst)[tt] = *(const bf16x8*)((W) +                                                 \
            (size_t)((((ks)*16 + wv * 2 + tt) * 64 + lane)) * 8);                          \
    }
// bf16 A-tile frag read (phase 3): rows tt*32+l31, bytes ks*32 + hi5*16
#define LDT32(dst, ks)                                                                     \
    _Pragma("unroll") for (int tt = 0; tt < 2; ++tt) {                                     \
        int row = tt * 32 + l31;                                                           \
        (dst)[tt] = *(const bf16x8*)((char*)A + row * 1024 +                               \
                                     SWZ(row, (ks)*32 + hi5 * 16));                        \
    }
// K-slice step, DIRECT bf16 (phase 3): ACC[mt][ct] += AO[mt] * W[ct]
#define GSTEP_O(W, ACC, WBASE, kk)                                                         \
    {                                                                                      \
        bf16x8 hb[2];                                                                      \
        LDT32(hb, (kk));                                                                   \
        _Pragma("unroll") for (int mt = 0; mt < 2; ++mt)                                   \
            _Pragma("unroll") for (int ct = 0; ct < 2; ++ct)                               \
                ACC[mt][ct] = MFMA32(hb[mt], (W)[ct], ACC[mt][ct]);                        \
        LDWF((W), (WBASE), (kk) + 4);                                                      \
    }
#define GSTEP_O_NR(W, ACC, kk)                                                             \
    {                                                                                      \
        bf16x8 hb[2];                                                                      \
        LDT32(hb, (kk));                                                                   \
        _Pragma("unroll") for (int mt = 0; mt < 2; ++mt)                                   \
            _Pragma("unroll") for (int ct = 0; ct < 2; ++ct)                               \
                ACC[mt][ct] = MFMA32(hb[mt], (W)[ct], ACC[mt][ct]);                        \
    }

    // ---- Phase 1: Q = h @ Wq via swapped fp8 32x32: D = mfma(WqF8, h^T) = q^T ----
    {
        long w0[2], w1[2], w2[2], w3[2];
        LDWF8(w0, 0);  // 4-deep prefetch issued before the barrier
        LDWF8(w1, 1);
        LDWF8(w2, 2);
        LDWF8(w3, 3);
        __syncthreads();   // h complete

        f32x16 qa[2][2];  // [mt=qcol tile][nt=qrow tile]
#pragma unroll
        for (int mt = 0; mt < 2; ++mt)
#pragma unroll
            for (int nt = 0; nt < 2; ++nt)
#pragma unroll
                for (int i = 0; i < 16; ++i) qa[mt][nt][i] = 0.f;

#pragma unroll 1
        for (int ks = 0; ks < 28; ks += 4) {  // refills target slices 4..31
            GSTEP_Q8(w0, qa, ks)
            GSTEP_Q8(w1, qa, ks + 1)
            GSTEP_Q8(w2, qa, ks + 2)
            GSTEP_Q8(w3, qa, ks + 3)
        }
        GSTEP_Q8_NR(w0, qa, 28)  // last 4 slices: no refill, no over-read
        GSTEP_Q8_NR(w1, qa, 29)
        GSTEP_Q8_NR(w2, qa, 30)
        GSTEP_Q8_NR(w3, qa, 31)
        __syncthreads();  // all waves done reading h

        // q writeback: fold 0.125 QK scale AND 1/WQ_SCALE fp8 descale
        const float QS = 0.125f / WQ_SCALE;
#pragma unroll
        for (int mt = 0; mt < 2; ++mt)
#pragma unroll
            for (int nt = 0; nt < 2; ++nt)
#pragma unroll
                for (int g = 0; g < 4; ++g) {
                    uint2 qv = make_uint2(
                        cvtpk(qa[mt][nt][g * 4] * QS, qa[mt][nt][g * 4 + 1] * QS),
                        cvtpk(qa[mt][nt][g * 4 + 2] * QS, qa[mt][nt][g * 4 + 3] * QS));
                    int row = nt * 32 + l31;
                    int colb = (cb + mt * 32 + 8 * g + 4 * hi5) * 2;
                    *(uint2*)((char*)A + row * 1024 + SWZ(row, colb)) = qv;
                }
        // no barrier: each wave reads only its own 64 columns from here
    }

    // ---- Phase 2: attention for head wv (16x16 bf16, swapped PV, P in regs) ----
    {
        const int srcA = ((l4 & 1) << 5) + l15;
        const int srcB = srcA + 16;
        const bool hi = (l4 >> 1) != 0;

        // V fragments are rp-invariant: hoist out of the rp loop (48 VGPRs)
        bf16x8 vR[3][4];
#pragma unroll
        for (int ks = 0; ks < 3; ++ks)
#pragma unroll
            for (int nb = 0; nb < 4; ++nb)
                vR[ks][nb] = *(const bf16x8*)(VbT +
                                              ((size_t)(b * 512 + cb + nb * 16 + l15)) * MPAD +
                                              ks * 32 + l4 * 8);

#pragma unroll 1
        for (int rp = 0; rp < 4; ++rp) {
            bf16x8 qf0, qf1;
            {
                int qrow = rp * 16 + l15;
                qf0 = *(const bf16x8*)((char*)A + qrow * 1024 + SWZ(qrow, cb * 2 + l4 * 16));
                qf1 = *(const bf16x8*)((char*)A + qrow * 1024 + SWZ(qrow, cb * 2 + 64 + l4 * 16));
            }
            f32x4 sc[5];
            __builtin_amdgcn_s_setprio(1);
#pragma unroll
            for (int f = 0; f < 5; ++f) {
                bf16x8 k0 = *(const bf16x8*)(Kb + ((size_t)(b * MPAD + f * 16 + l15)) * 512 +
                                             cb + l4 * 8);
                bf16x8 k1 = *(const bf16x8*)(Kb + ((size_t)(b * MPAD + f * 16 + l15)) * 512 +
                                             cb + 32 + l4 * 8);
                sc[f] = MFMA(k0, qf0, zf);
                sc[f] = MFMA(k1, qf1, sc[f]);
            }
            __builtin_amdgcn_s_setprio(0);
            // q was pre-scaled at writeback; scores are final here
            float m = -1e30f;
#pragma unroll
            for (int f = 0; f < 5; ++f)
#pragma unroll
                for (int r = 0; r < 4; ++r) {
                    float v = sc[f][r];
                    if (f == 4 && (64 + l4 * 4 + r) >= MCTX) v = -1e30f;
                    sc[f][r] = v;
                    m = fmaxf(m, v);
                }
            m = fmaxf(m, __shfl_xor(m, 16));
            m = fmaxf(m, __shfl_xor(m, 32));
            float s = 0.f;
#pragma unroll
            for (int f = 0; f < 5; ++f)
#pragma unroll
                for (int r = 0; r < 4; ++r) {
                    float p = __expf(sc[f][r] - m);
                    sc[f][r] = p;
                    s += p;
                }
            s += __shfl_xor(s, 16);
            s += __shfl_xor(s, 32);
            float inv = 1.f / s;
            unsigned pk[6][2];
#pragma unroll
            for (int f = 0; f < 5; ++f) {
                pk[f][0] = cvtpk(sc[f][0] * inv, sc[f][1] * inv);
                pk[f][1] = cvtpk(sc[f][2] * inv, sc[f][3] * inv);
            }
            pk[5][0] = 0; pk[5][1] = 0;
            unsigned pa[3][4];
#pragma unroll
            for (int ks = 0; ks < 3; ++ks) {
                unsigned aL0 = __shfl((int)pk[2 * ks][0], srcA);
                unsigned aL1 = __shfl((int)pk[2 * ks][1], srcA);
                unsigned aH0 = __shfl((int)pk[2 * ks + 1][0], srcA);
                unsigned aH1 = __shfl((int)pk[2 * ks + 1][1], srcA);
                unsigned bL0 = __shfl((int)pk[2 * ks][0], srcB);
                unsigned bL1 = __shfl((int)pk[2 * ks][1], srcB);
                unsigned bH0 = __shfl((int)pk[2 * ks + 1][0], srcB);
                unsigned bH1 = __shfl((int)pk[2 * ks + 1][1], srcB);
                pa[ks][0] = hi ? aH0 : aL0;
                pa[ks][1] = hi ? aH1 : aL1;
                pa[ks][2] = hi ? bH0 : bL0;
                pa[ks][3] = hi ? bH1 : bL1;
            }
            // PV swapped: D = mfma(A=V^T frag, B=P frag) = (PV)^T
            f32x4 ov[4];
#pragma unroll
            for (int nb = 0; nb < 4; ++nb) ov[nb] = zf;
            __builtin_amdgcn_s_setprio(1);
#pragma unroll
            for (int ks = 0; ks < 3; ++ks) {
                bf16x8 ap = __builtin_bit_cast(bf16x8, pa[ks]);
#pragma unroll
                for (int nb = 0; nb < 4; ++nb) {
                    ov[nb] = MFMA(vR[ks][nb], ap, ov[nb]);  // swapped args, V in regs
                }
            }
            __builtin_amdgcn_s_setprio(0);
            // AO writeback (bf16): row = q-row, 4 consecutive dim cols
#pragma unroll
            for (int nb = 0; nb < 4; ++nb) {
                uint2 av = make_uint2(cvtpk(ov[nb][0], ov[nb][1]),
                                      cvtpk(ov[nb][2], ov[nb][3]));
                int row = rp * 16 + l15;
                int colb = (cb + nb * 16 + l4 * 4) * 2;
                *(uint2*)((char*)A + row * 1024 + SWZ(row, colb)) = av;
            }
        }
    }

    // ---- Phase 3: O-proj 32x32 bf16 (K=512, direct) + residual + bias ----
    {
        bf16x8 w0[2], w1[2], w2[2], w3[2];
        LDWF(w0, WoF, 0);  // 4-deep prefetch issued before the barrier
        LDWF(w1, WoF, 1);
        LDWF(w2, WoF, 2);
        LDWF(w3, WoF, 3);
        __syncthreads();   // AO complete across all waves

        f32x16 oa[2][2];  // [mt=row tile][ct=col tile]
#pragma unroll
        for (int mt = 0; mt < 2; ++mt)
#pragma unroll
            for (int ct = 0; ct < 2; ++ct)
#pragma unroll
                for (int i = 0; i < 16; ++i) oa[mt][ct][i] = 0.f;

#pragma unroll 1
        for (int ks = 0; ks < 28; ks += 4) {  // refills target slices 4..31
            GSTEP_O(w0, oa, WoF, ks)
            GSTEP_O(w1, oa, WoF, ks + 1)
            GSTEP_O(w2, oa, WoF, ks + 2)
            GSTEP_O(w3, oa, WoF, ks + 3)
        }
        GSTEP_O_NR(w0, oa, 28)  // last 4 slices: no refill, no over-read
        GSTEP_O_NR(w1, oa, 29)
        GSTEP_O_NR(w2, oa, 30)
        GSTEP_O_NR(w3, oa, 31)

        // epilogue: out = x + oa + bo; lane = out-col (coalesced), regs = rows
#pragma unroll
        for (int mt = 0; mt < 2; ++mt)
#pragma unroll
            for (int ct = 0; ct < 2; ++ct) {
                int col = cb + ct * 32 + l31;
                float bov = bo[col];
                float xv[16];
#pragma unroll
                for (int rg = 0; rg < 16; ++rg) {
                    int row = mt * 32 + (rg & 3) + 8 * (rg >> 2) + 4 * hi5;
                    xv[rg] = x[(rowbase + row) * DQ + col];
                }
#pragma unroll
                for (int rg = 0; rg < 16; ++rg) {
                    int row = mt * 32 + (rg & 3) + 8 * (rg >> 2) + 4 * hi5;
                    size_t gi = (rowbase + row) * DQ + col;
                    out[gi] = xv[rg] + oa[mt][ct][rg] + bov;
                }
            }
    }
}

// ---------------------------------------------------------------------------
extern "C" void kernel_launch(void* const* d_in, const int* in_sizes, int n_in,
                              void* d_out, int out_size, void* d_ws, size_t ws_size,
                              hipStream_t stream) {
    const float* x = (const float*)d_in[0];
    const float* ctx = (const float*)d_in[1];
    const float* gamma = (const float*)d_in[2];
    const float* beta = (const float*)d_in[3];
    const float* Wq = (const float*)d_in[4];
    const float* Wk = (const float*)d_in[5];
    const float* Wv = (const float*)d_in[6];
    const float* Wo = (const float*)d_in[7];
    const float* bo = (const float*)d_in[8];
    float* out = (float*)d_out;

    char* ws = (char*)d_ws;
    unsigned char* WqF8 = (unsigned char*)(ws + 0);  // fp8 flat [32ks][16t][64lane][8B]
    short* WkT = (short*)(ws + 524288);   // [512][768] row-major W^T
    short* WvT = (short*)(ws + 1310720);  // [512][768]
    short* WoF = (short*)(ws + 2097152);  // bf16 32x32-frag flat
    short* Kb = (short*)(ws + 2621440);   // [16][96][512]  K: [b][ctx][dim]
    short* VbT = (short*)(ws + 4194304);  // [16][512][96]  V: [b][dim][ctx]

    prep_weights<<<1024, 256, 0, stream>>>(Wq, Wk, Wv, Wo, WqF8, WkT, WvT, WoF);
    kv_proj<<<64, 256, 0, stream>>>(ctx, WkT, WvT, Kb, VbT);
    fused_attn<<<1024, 512, 0, stream>>>(x, gamma, beta, WqF8, WoF, Kb, VbT, bo, out);
}